// Round 11
// baseline (2367.702 us; speedup 1.0000x reference)
//
#include <hip/hip_runtime.h>
#include <math.h>

constexpr int KIN = 128;     // IN_F
constexpr int GRID = 1536;   // 256 CU x 6 blocks/CU, 256 thr (24 KB LDS max)

// ---------------- device-scope grid barrier (all GRID blocks co-resident) ----------------
__device__ inline void gridbar(int* cnt, int* gen) {
    __syncthreads();
    if (threadIdx.x == 0) {
        __threadfence();
        int g = atomicAdd(gen, 0);
        if (atomicAdd(cnt, 1) == GRID - 1) {
            atomicExch(cnt, 0);
            atomicAdd(gen, 1);
        } else {
            while (atomicAdd(gen, 0) == g) __builtin_amdgcn_s_sleep(1);
        }
        __threadfence();
    }
    __syncthreads();
}

// exclusive block scan over 256 lanes; tmp = 256 ints; returns exclusive prefix
__device__ inline int block_scan_excl(int v, int* tmp) {
    int t = threadIdx.x;
    tmp[t] = v;
    __syncthreads();
    for (int off = 1; off < 256; off <<= 1) {
        int x = (t >= off) ? tmp[t - off] : 0;
        __syncthreads();
        tmp[t] += x;
        __syncthreads();
    }
    int incl = tmp[t];
    __syncthreads();
    return incl - v;
}

// ---------------- agg device functions (R7-proven bodies, grid-stride) ----------------
template <int MODE>  // 1: dinv*relu(dinv*acc+b); 2: raw sum
__device__ void agg32_phase(const float* __restrict__ Hs, const int* __restrict__ row_ptr,
                            const int* __restrict__ csr, const float* __restrict__ dinv,
                            const float* __restrict__ bias, float* __restrict__ out, int n) {
    int wid = threadIdx.x >> 6, lane = threadIdx.x & 63;
    int cg = lane & 7, slot = lane >> 3;   // CG=8, SLOTS=8
    const float4* H4 = (const float4*)Hs;
    for (int v = blockIdx.x * 4 + wid; v < n; v += GRID * 4) {
        float4 acc = {0.f, 0.f, 0.f, 0.f};
        if (slot == 0) acc = H4[(size_t)v * 8 + cg];
        int beg = row_ptr[v], end = row_ptr[v + 1];
        int iters = (end - beg + 7) >> 3;
        int e = beg + slot;
        bool val = e < end;
        int u = val ? csr[e] : v;
        float4 h = H4[(size_t)u * 8 + cg];
        for (int i = 0; i < iters; ++i) {
            int en = e + 8;
            bool valn = en < end;
            int un = valn ? csr[en] : v;
            float4 hn = H4[(size_t)un * 8 + cg];
            float m = val ? 1.f : 0.f;
            acc.x = fmaf(m, h.x, acc.x); acc.y = fmaf(m, h.y, acc.y);
            acc.z = fmaf(m, h.z, acc.z); acc.w = fmaf(m, h.w, acc.w);
            e = en; val = valn; h = hn;
        }
        for (int off = 8; off < 64; off <<= 1) {
            acc.x += __shfl_xor(acc.x, off); acc.y += __shfl_xor(acc.y, off);
            acc.z += __shfl_xor(acc.z, off); acc.w += __shfl_xor(acc.w, off);
        }
        if (slot == 0) {
            float4 o;
            if (MODE == 2) {
                o = acc;
            } else {
                float dv = dinv[v];
                o.x = fmaxf(fmaf(dv, acc.x, bias[4 * cg + 0]), 0.f) * dv;
                o.y = fmaxf(fmaf(dv, acc.y, bias[4 * cg + 1]), 0.f) * dv;
                o.z = fmaxf(fmaf(dv, acc.z, bias[4 * cg + 2]), 0.f) * dv;
                o.w = fmaxf(fmaf(dv, acc.w, bias[4 * cg + 3]), 0.f) * dv;
            }
            ((float4*)out)[(size_t)v * 8 + cg] = o;
        }
    }
}

__device__ void gcn64_phase(const float* __restrict__ Hs, const int* __restrict__ row_ptr,
                            const int* __restrict__ csr, const float* __restrict__ dinv,
                            const float* __restrict__ bias, const float* __restrict__ res,
                            float* __restrict__ out, int n) {
    int wid = threadIdx.x >> 6, lane = threadIdx.x & 63;
    int cg = lane & 15, slot = lane >> 4;   // CG=16, SLOTS=4
    const float4* H4 = (const float4*)Hs;
    for (int v = blockIdx.x * 4 + wid; v < n; v += GRID * 4) {
        float4 acc = {0.f, 0.f, 0.f, 0.f};
        if (slot == 0) acc = H4[(size_t)v * 16 + cg];
        int beg = row_ptr[v], end = row_ptr[v + 1];
        int iters = (end - beg + 3) >> 2;
        int e = beg + slot;
        bool val = e < end;
        int u = val ? csr[e] : v;
        float4 h = H4[(size_t)u * 16 + cg];
        for (int i = 0; i < iters; ++i) {
            int en = e + 4;
            bool valn = en < end;
            int un = valn ? csr[en] : v;
            float4 hn = H4[(size_t)un * 16 + cg];
            float m = val ? 1.f : 0.f;
            acc.x = fmaf(m, h.x, acc.x); acc.y = fmaf(m, h.y, acc.y);
            acc.z = fmaf(m, h.z, acc.z); acc.w = fmaf(m, h.w, acc.w);
            e = en; val = valn; h = hn;
        }
        for (int off = 16; off < 64; off <<= 1) {
            acc.x += __shfl_xor(acc.x, off); acc.y += __shfl_xor(acc.y, off);
            acc.z += __shfl_xor(acc.z, off); acc.w += __shfl_xor(acc.w, off);
        }
        if (slot == 0) {
            float dv = dinv[v];
            const float4 r = ((const float4*)res)[(size_t)v * 16 + cg];
            float4 o;
            o.x = fmaxf(fmaf(dv, acc.x, bias[4 * cg + 0]), 0.f) + r.x;
            o.y = fmaxf(fmaf(dv, acc.y, bias[4 * cg + 1]), 0.f) + r.y;
            o.z = fmaxf(fmaf(dv, acc.z, bias[4 * cg + 2]), 0.f) + r.z;
            o.w = fmaxf(fmaf(dv, acc.w, bias[4 * cg + 3]), 0.f) + r.w;
            ((float4*)out)[(size_t)v * 16 + cg] = o;
        }
    }
}

template <bool FINAL>
__device__ void gat64_phase(const float* __restrict__ H, const int* __restrict__ row_ptr,
                            const int* __restrict__ csr, const float* __restrict__ a_s,
                            const float* __restrict__ a_d, const float* __restrict__ bias,
                            const float* __restrict__ Wl, const float* __restrict__ bl,
                            float* __restrict__ out, int n) {
    int wid = threadIdx.x >> 6, lane = threadIdx.x & 63;
    int cg = lane & 15, slot = lane >> 4, hd = cg >> 2;
    const float4* H4 = (const float4*)H;
    for (int v = blockIdx.x * 4 + wid; v < n; v += GRID * 4) {
        float adv = a_d[v * 4 + hd];
        float l = 0.f;
        float4 acc = {0.f, 0.f, 0.f, 0.f};
        if (slot == 0) {
            float e0 = a_s[v * 4 + hd] + adv;
            e0 = (e0 >= 0.f) ? e0 : 0.2f * e0;
            float p = __expf(e0);
            l = p;
            float4 h = H4[(size_t)v * 16 + cg];
            acc.x = p * h.x; acc.y = p * h.y; acc.z = p * h.z; acc.w = p * h.w;
        }
        int beg = row_ptr[v], end = row_ptr[v + 1];
        int iters = (end - beg + 3) >> 2;
        int e = beg + slot;
        bool val = e < end;
        int u = val ? csr[e] : v;
        float4 h = H4[(size_t)u * 16 + cg];
        float as = a_s[u * 4 + hd];
        for (int i = 0; i < iters; ++i) {
            int en = e + 4;
            bool valn = en < end;
            int un = valn ? csr[en] : v;
            float4 hn = H4[(size_t)un * 16 + cg];
            float asn = a_s[un * 4 + hd];
            float ev = as + adv;
            ev = (ev >= 0.f) ? ev : 0.2f * ev;
            float p = val ? __expf(ev) : 0.f;
            l += p;
            acc.x = fmaf(p, h.x, acc.x); acc.y = fmaf(p, h.y, acc.y);
            acc.z = fmaf(p, h.z, acc.z); acc.w = fmaf(p, h.w, acc.w);
            e = en; val = valn; h = hn; as = asn;
        }
        for (int off = 16; off < 64; off <<= 1) {
            l += __shfl_xor(l, off);
            acc.x += __shfl_xor(acc.x, off); acc.y += __shfl_xor(acc.y, off);
            acc.z += __shfl_xor(acc.z, off); acc.w += __shfl_xor(acc.w, off);
        }
        float rl = 1.0f / (l + 1e-16f);
        if (!FINAL) {
            if (slot == 0) {
                float4 o;
                o.x = fmaxf(fmaf(acc.x, rl, bias[4 * cg + 0]), 0.f);
                o.y = fmaxf(fmaf(acc.y, rl, bias[4 * cg + 1]), 0.f);
                o.z = fmaxf(fmaf(acc.z, rl, bias[4 * cg + 2]), 0.f);
                o.w = fmaxf(fmaf(acc.w, rl, bias[4 * cg + 3]), 0.f);
                ((float4*)out)[(size_t)v * 16 + cg] = o;
            }
        } else {
            float p = fmaxf(fmaf(acc.x, rl, bias[4 * cg + 0]), 0.f) * Wl[4 * cg + 0]
                    + fmaxf(fmaf(acc.y, rl, bias[4 * cg + 1]), 0.f) * Wl[4 * cg + 1]
                    + fmaxf(fmaf(acc.z, rl, bias[4 * cg + 2]), 0.f) * Wl[4 * cg + 2]
                    + fmaxf(fmaf(acc.w, rl, bias[4 * cg + 3]), 0.f) * Wl[4 * cg + 3];
            p += __shfl_xor(p, 1);
            p += __shfl_xor(p, 2);
            p += __shfl_xor(p, 4);
            p += __shfl_xor(p, 8);
            if (lane == 0) out[v] = fmaxf(p + bl[0], 0.f);
        }
    }
}

// K=64-chunked 64x64 GEMM phase, LDS = xs(32*64) + Ws(32*64) = 16 KB
template <bool SCALE, bool ATT>
__device__ void gemm64_phase(const float* __restrict__ in, const float* __restrict__ W,
                             const float* __restrict__ dinv, const float* __restrict__ att_src,
                             const float* __restrict__ att_dst, float* __restrict__ a_s,
                             float* __restrict__ a_d, float* __restrict__ out, int n,
                             float* xs, float* Ws) {
    int t = threadIdx.x;
    int tx = t & 15, ty = t >> 4;
    int tiles = (n + 63) >> 6;
    for (int tile = blockIdx.x; tile < tiles; tile += GRID) {
        int row0 = tile * 64;
        float acc[4][4] = {};
#pragma unroll
        for (int c = 0; c < 2; ++c) {
            __syncthreads();
            for (int i = t; i < 512; i += 256)
                ((float4*)Ws)[i] = ((const float4*)W)[c * 512 + i];
            for (int i = t; i < 512; i += 256) {
                int r = i & 63, k4 = i >> 6;
                int row = row0 + r;
                float4 v = {0.f, 0.f, 0.f, 0.f};
                if (row < n) v = ((const float4*)(in + (size_t)row * 64))[c * 8 + k4];
                xs[(4 * k4 + 0) * 64 + r] = v.x;
                xs[(4 * k4 + 1) * 64 + r] = v.y;
                xs[(4 * k4 + 2) * 64 + r] = v.z;
                xs[(4 * k4 + 3) * 64 + r] = v.w;
            }
            __syncthreads();
#pragma unroll 4
            for (int k = 0; k < 32; ++k) {
                float4 xv = *(const float4*)&xs[k * 64 + ty * 4];
                float4 wv = *(const float4*)&Ws[k * 64 + tx * 4];
                float xr[4] = {xv.x, xv.y, xv.z, xv.w};
                float wr[4] = {wv.x, wv.y, wv.z, wv.w};
#pragma unroll
                for (int i = 0; i < 4; ++i)
#pragma unroll
                    for (int j = 0; j < 4; ++j)
                        acc[i][j] = fmaf(xr[i], wr[j], acc[i][j]);
            }
        }
#pragma unroll
        for (int i = 0; i < 4; ++i) {
            int row = row0 + ty * 4 + i;
            if (row >= n) continue;
            float s = SCALE ? dinv[row] : 1.0f;
            float4 o = {acc[i][0] * s, acc[i][1] * s, acc[i][2] * s, acc[i][3] * s};
            ((float4*)(out + (size_t)row * 64))[tx] = o;
        }
        if (ATT) {
            int hd = tx >> 2;
            float as0 = att_src[4 * tx + 0], as1 = att_src[4 * tx + 1];
            float as2 = att_src[4 * tx + 2], as3 = att_src[4 * tx + 3];
            float ad0 = att_dst[4 * tx + 0], ad1 = att_dst[4 * tx + 1];
            float ad2 = att_dst[4 * tx + 2], ad3 = att_dst[4 * tx + 3];
#pragma unroll
            for (int i = 0; i < 4; ++i) {
                float ps = acc[i][0] * as0 + acc[i][1] * as1 + acc[i][2] * as2 + acc[i][3] * as3;
                float pd = acc[i][0] * ad0 + acc[i][1] * ad1 + acc[i][2] * ad2 + acc[i][3] * ad3;
                ps += __shfl_xor(ps, 1); pd += __shfl_xor(pd, 1);
                ps += __shfl_xor(ps, 2); pd += __shfl_xor(pd, 2);
                int row = row0 + ty * 4 + i;
                if ((tx & 3) == 0 && row < n) {
                    a_s[row * 4 + hd] = ps;
                    a_d[row * 4 + hd] = pd;
                }
            }
        }
    }
}

// ---------------- megakernel A: graph build + gemm1 + two 32-dim aggs ----------------
__global__ void __launch_bounds__(256, 6)
megaA(const float* __restrict__ x, const int* __restrict__ srcp, const int* __restrict__ dstp,
      const float* __restrict__ W1, const float* __restrict__ b1,
      int* __restrict__ hist_g, int* __restrict__ partial, int* __restrict__ bpre,
      int* __restrict__ excl, int* __restrict__ p1, int* __restrict__ csr,
      int* __restrict__ row_ptr, float* __restrict__ dinv,
      float* __restrict__ bufA, float* __restrict__ bufB,
      int n, int E, int NBKT, int* cnt, int* gen) {
    __shared__ float smem[6144];  // 24 KB
    int* smemi = (int*)smem;
    int t = threadIdx.x, b = blockIdx.x;
    int CH = (E + GRID - 1) / GRID;

    // P1: per-chunk histogram of dst>>9
    {
        for (int i = t; i < 256; i += 256) smemi[i] = 0;
        __syncthreads();
        int beg = b * CH, end = min(beg + CH, E);
        for (int e = beg + t; e < end; e += 256) atomicAdd(&smemi[dstp[e] >> 9], 1);
        __syncthreads();
        for (int d = t; d < NBKT; d += 256) hist_g[d * GRID + b] = smemi[d];
    }
    gridbar(cnt, gen);

    // P2a: per-block slice sums (slice = NBKT elements)
    {
        int v = (t < NBKT) ? hist_g[b * NBKT + t] : 0;
        smemi[t] = v;
        __syncthreads();
        for (int off = 128; off > 0; off >>= 1) {
            if (t < off) smemi[t] += smemi[t + off];
            __syncthreads();
        }
        if (t == 0) partial[b] = smemi[0];
    }
    gridbar(cnt, gen);

    // P2b: block 0 scans GRID partials (6 per thread)
    if (b == 0) {
        int vals[6], s = 0;
#pragma unroll
        for (int i = 0; i < 6; ++i) { vals[i] = partial[t * 6 + i]; s += vals[i]; }
        int ex = block_scan_excl(s, smemi);
#pragma unroll
        for (int i = 0; i < 6; ++i) { bpre[t * 6 + i] = ex; ex += vals[i]; }
    } else {
        block_scan_excl(0, smemi);  // keep syncthreads counts uniform (per-block only, fine)
    }
    gridbar(cnt, gen);

    // P2c: per-block slice exclusive scan + offset
    {
        int v = (t < NBKT) ? hist_g[b * NBKT + t] : 0;
        int ex = block_scan_excl(v, smemi);
        if (t < NBKT) excl[b * NBKT + t] = bpre[b] + ex;
    }
    gridbar(cnt, gen);
    // NOTE: excl is indexed flat [i]; flat i = d*GRID + b_chunk. Slice of block b covers
    // flat [b*NBKT, (b+1)*NBKT) — SAME flat ordering, so excl[d*GRID + bc] is valid below.

    // P3: scatter edges into bucket order (packed (dst&511)<<17 | src)
    {
        for (int d = t; d < NBKT; d += 256) smemi[d] = excl[d * GRID + b];
        __syncthreads();
        int beg = b * CH, end = min(beg + CH, E);
        for (int e = beg + t; e < end; e += 256) {
            int dd = dstp[e];
            int pos = atomicAdd(&smemi[dd >> 9], 1);
            p1[pos] = ((dd & 511) << 17) | srcp[e];
        }
    }
    gridbar(cnt, gen);

    // P4: per-bucket counting sort (blocks 0..NBKT-1), 256 thr x 512 bins
    if (b < NBKT) {
        int* histS = smemi;          // 512
        int* scanS = smemi + 512;    // 256
        int* offsS = smemi + 768;    // 512
        int base = excl[b * GRID];
        int endb = (b + 1 < NBKT) ? excl[(b + 1) * GRID] : E;
        histS[t] = 0; histS[t + 256] = 0;
        __syncthreads();
        for (int i = base + t; i < endb; i += 256) atomicAdd(&histS[p1[i] >> 17], 1);
        __syncthreads();
        int v0 = histS[2 * t], v1 = histS[2 * t + 1];
        int ex = block_scan_excl(v0 + v1, scanS);
        offsS[2 * t] = ex;
        offsS[2 * t + 1] = ex + v0;
        int node0 = b * 512 + 2 * t;
        if (node0 < n)     { row_ptr[node0] = base + ex;      dinv[node0] = 1.0f / sqrtf((float)(v0 + 1)); }
        if (node0 + 1 < n) { row_ptr[node0 + 1] = base + ex + v0; dinv[node0 + 1] = 1.0f / sqrtf((float)(v1 + 1)); }
        if (b == NBKT - 1 && t == 0) row_ptr[n] = E;
        __syncthreads();
        for (int i = base + t; i < endb; i += 256) {
            int p = p1[i];
            int pos = atomicAdd(&offsS[p >> 17], 1);
            csr[base + pos] = p & 0x1FFFF;
        }
    }
    gridbar(cnt, gen);

    // P5: gemm1 (128->32), K chunked by 64; LDS xs 16KB + Ws 8KB
    {
        float* xs = smem;          // 64x64
        float* Ws = smem + 4096;   // 64x32 per chunk
        int tx = t & 7, ty = t >> 3;
        int tiles = (n + 63) >> 6;
        for (int tile = b; tile < tiles; tile += GRID) {
            int row0 = tile * 64;
            float acc[2][4] = {};
#pragma unroll
            for (int c = 0; c < 2; ++c) {
                __syncthreads();
                for (int i = t; i < 512; i += 256)
                    ((float4*)Ws)[i] = ((const float4*)W1)[c * 512 + i];
                for (int i = t; i < 1024; i += 256) {
                    int r = i & 63, k4 = i >> 6;
                    int row = row0 + r;
                    float4 v = {0.f, 0.f, 0.f, 0.f};
                    if (row < n) v = ((const float4*)(x + (size_t)row * 128))[c * 16 + k4];
                    xs[(4 * k4 + 0) * 64 + r] = v.x;
                    xs[(4 * k4 + 1) * 64 + r] = v.y;
                    xs[(4 * k4 + 2) * 64 + r] = v.z;
                    xs[(4 * k4 + 3) * 64 + r] = v.w;
                }
                __syncthreads();
#pragma unroll 4
                for (int k = 0; k < 64; ++k) {
                    float2 xv = *(const float2*)&xs[k * 64 + ty * 2];
                    float4 wv = *(const float4*)&Ws[k * 32 + tx * 4];
                    acc[0][0] = fmaf(xv.x, wv.x, acc[0][0]);
                    acc[0][1] = fmaf(xv.x, wv.y, acc[0][1]);
                    acc[0][2] = fmaf(xv.x, wv.z, acc[0][2]);
                    acc[0][3] = fmaf(xv.x, wv.w, acc[0][3]);
                    acc[1][0] = fmaf(xv.y, wv.x, acc[1][0]);
                    acc[1][1] = fmaf(xv.y, wv.y, acc[1][1]);
                    acc[1][2] = fmaf(xv.y, wv.z, acc[1][2]);
                    acc[1][3] = fmaf(xv.y, wv.w, acc[1][3]);
                }
            }
#pragma unroll
            for (int i = 0; i < 2; ++i) {
                int row = row0 + ty * 2 + i;
                if (row >= n) continue;
                float s = dinv[row];
                float4 o = {acc[i][0] * s, acc[i][1] * s, acc[i][2] * s, acc[i][3] * s};
                ((float4*)(bufA + (size_t)row * 32))[tx] = o;
            }
        }
    }
    gridbar(cnt, gen);

    // P6: layer-1 agg (MODE1): bufA -> bufB  (G = dinv*relu(dinv*agg+b1))
    agg32_phase<1>(bufA, row_ptr, csr, dinv, b1, bufB, n);
    gridbar(cnt, gen);

    // P7: layer-2 raw-sum agg (MODE2): bufB -> bufA  (T)
    agg32_phase<2>(bufB, row_ptr, csr, nullptr, nullptr, bufA, n);
}

// ---------------- kernel B: fused layer2-GEMM + GAT1-GEMM (unchanged, 49 KB LDS) ----------------
__global__ void __launch_bounds__(256)
gemm2_gat(const float* __restrict__ T, const float* __restrict__ W2,
          const float* __restrict__ b2, const float* __restrict__ dinv,
          const float* __restrict__ Wg, const float* __restrict__ att_src,
          const float* __restrict__ att_dst, float* __restrict__ a_s,
          float* __restrict__ a_d, float* __restrict__ A1, int n) {
    __shared__ float xs[32][64];
    __shared__ float W2s[32 * 64];
    __shared__ float Wgs[64 * 64];
    __shared__ float hs[64][68];
    int t = threadIdx.x;
    int row0 = blockIdx.x * 64;

    for (int i = t; i < 32 * 64 / 4; i += 256) ((float4*)W2s)[i] = ((const float4*)W2)[i];
    for (int i = t; i < 64 * 64 / 4; i += 256) ((float4*)Wgs)[i] = ((const float4*)Wg)[i];
    for (int i = t; i < 64 * 8; i += 256) {
        int r = i % 64, k4 = i / 64;
        int row = row0 + r;
        float4 v = {0.f, 0.f, 0.f, 0.f};
        if (row < n) v = ((const float4*)(T + (size_t)row * 32))[k4];
        xs[4 * k4 + 0][r] = v.x;
        xs[4 * k4 + 1][r] = v.y;
        xs[4 * k4 + 2][r] = v.z;
        xs[4 * k4 + 3][r] = v.w;
    }
    __syncthreads();

    int tx = t % 16, ty = t / 16;
    {
        float acc[4][4] = {};
#pragma unroll 4
        for (int k = 0; k < 32; ++k) {
            float4 xv = *(const float4*)&xs[k][ty * 4];
            float4 wv = *(const float4*)&W2s[k * 64 + tx * 4];
            float xr[4] = {xv.x, xv.y, xv.z, xv.w};
            float wr[4] = {wv.x, wv.y, wv.z, wv.w};
#pragma unroll
            for (int i = 0; i < 4; ++i)
#pragma unroll
                for (int j = 0; j < 4; ++j)
                    acc[i][j] = fmaf(xr[i], wr[j], acc[i][j]);
        }
#pragma unroll
        for (int i = 0; i < 4; ++i) {
            int row = row0 + ty * 4 + i;
            float s = (row < n) ? dinv[row] : 0.f;
#pragma unroll
            for (int j = 0; j < 4; ++j)
                hs[4 * tx + j][ty * 4 + i] = fmaxf(fmaf(acc[i][j], s, b2[4 * tx + j]), 0.f);
        }
    }
    __syncthreads();

    float acc[4][4] = {};
#pragma unroll 4
    for (int k = 0; k < 64; ++k) {
        float4 xv = *(const float4*)&hs[k][ty * 4];
        float4 wv = *(const float4*)&Wgs[k * 64 + tx * 4];
        float xr[4] = {xv.x, xv.y, xv.z, xv.w};
        float wr[4] = {wv.x, wv.y, wv.z, wv.w};
#pragma unroll
        for (int i = 0; i < 4; ++i)
#pragma unroll
            for (int j = 0; j < 4; ++j)
                acc[i][j] = fmaf(xr[i], wr[j], acc[i][j]);
    }
#pragma unroll
    for (int i = 0; i < 4; ++i) {
        int row = row0 + ty * 4 + i;
        if (row >= n) continue;
        float4 o = {acc[i][0], acc[i][1], acc[i][2], acc[i][3]};
        ((float4*)(A1 + (size_t)row * 64))[tx] = o;
    }
    {
        int hd = tx >> 2;
        float as0 = att_src[4 * tx + 0], as1 = att_src[4 * tx + 1];
        float as2 = att_src[4 * tx + 2], as3 = att_src[4 * tx + 3];
        float ad0 = att_dst[4 * tx + 0], ad1 = att_dst[4 * tx + 1];
        float ad2 = att_dst[4 * tx + 2], ad3 = att_dst[4 * tx + 3];
#pragma unroll
        for (int i = 0; i < 4; ++i) {
            float ps = acc[i][0] * as0 + acc[i][1] * as1 + acc[i][2] * as2 + acc[i][3] * as3;
            float pd = acc[i][0] * ad0 + acc[i][1] * ad1 + acc[i][2] * ad2 + acc[i][3] * ad3;
            ps += __shfl_xor(ps, 1); pd += __shfl_xor(pd, 1);
            ps += __shfl_xor(ps, 2); pd += __shfl_xor(pd, 2);
            int row = row0 + ty * 4 + i;
            if ((tx & 3) == 0 && row < n) {
                a_s[row * 4 + hd] = ps;
                a_d[row * 4 + hd] = pd;
            }
        }
    }
}

// ---------------- megakernel C: back half (GAT1 agg ... final) ----------------
__global__ void __launch_bounds__(256, 6)
megaC(const int* __restrict__ row_ptr, const int* __restrict__ csr,
      float* __restrict__ a_s, float* __restrict__ a_d, const float* __restrict__ bg,
      const float* __restrict__ W3, const float* __restrict__ b3,
      const float* __restrict__ dinv, const float* __restrict__ Wg,
      const float* __restrict__ att_s, const float* __restrict__ att_d,
      const float* __restrict__ Wl, const float* __restrict__ bl,
      float* __restrict__ bufA, float* __restrict__ bufB, float* __restrict__ bufC,
      float* __restrict__ out, int n, int* cnt, int* gen) {
    __shared__ float smem[4096];  // 16 KB: xs + Ws
    float* xs = smem;
    float* Ws = smem + 2048;

    // P1: GAT1 agg: bufB(A1) -> bufC
    gat64_phase<false>(bufB, row_ptr, csr, a_s, a_d, bg, nullptr, nullptr, bufC, n);
    gridbar(cnt, gen);
    // P2: Hs3 = dinv*(bufC @ W3) -> bufA
    gemm64_phase<true, false>(bufC, W3, dinv, nullptr, nullptr, nullptr, nullptr, bufA, n, xs, Ws);
    gridbar(cnt, gen);
    // P3: GCN3 agg + residual: gather bufA, res bufC -> bufB
    gcn64_phase(bufA, row_ptr, csr, dinv, b3, bufC, bufB, n);
    gridbar(cnt, gen);
    // P4: A2 = bufB @ Wg -> bufA, attention dots
    gemm64_phase<false, true>(bufB, Wg, nullptr, att_s, att_d, a_s, a_d, bufA, n, xs, Ws);
    gridbar(cnt, gen);
    // P5: GAT2 agg + final linear -> out
    gat64_phase<true>(bufA, row_ptr, csr, a_s, a_d, bg, Wl, bl, out, n);
}

// ---------------- launch ----------------

extern "C" void kernel_launch(void* const* d_in, const int* in_sizes, int n_in,
                              void* d_out, int out_size, void* d_ws, size_t ws_size,
                              hipStream_t stream) {
    const float* x     = (const float*)d_in[0];
    const int*   ei    = (const int*)d_in[1];
    const float* W1    = (const float*)d_in[2];
    const float* b1    = (const float*)d_in[3];
    const float* W2    = (const float*)d_in[4];
    const float* b2    = (const float*)d_in[5];
    const float* W3    = (const float*)d_in[6];
    const float* b3    = (const float*)d_in[7];
    const float* Wg    = (const float*)d_in[8];
    const float* att_s = (const float*)d_in[9];
    const float* att_d = (const float*)d_in[10];
    const float* bg    = (const float*)d_in[11];
    const float* Wl    = (const float*)d_in[12];
    const float* bl    = (const float*)d_in[13];
    float* out = (float*)d_out;

    int n = in_sizes[0] / KIN;  // 100000 (< 2^17)
    int E = in_sizes[1] / 2;    // 1600000
    const int* srcp = ei;
    const int* dstp = ei + E;

    int NBKT = (n + 511) >> 9;  // 196
    int M = NBKT * GRID;

    char* w = (char*)d_ws;
    auto alloc = [&](size_t bytes) -> void* {
        void* p = (void*)w;
        w += (bytes + 255) & ~(size_t)255;
        return p;
    };
    int*   barrier = (int*)alloc(2 * 4);           // cnt, gen
    int*   row_ptr = (int*)alloc((size_t)(n + 1) * 4);
    int*   csr     = (int*)alloc((size_t)E * 4);
    int*   hist_g  = (int*)alloc((size_t)M * 4);
    int*   excl    = (int*)alloc((size_t)M * 4);
    int*   partial = (int*)alloc(GRID * 4);
    int*   bpre    = (int*)alloc(GRID * 4);
    float* dinv    = (float*)alloc((size_t)n * 4);
    float* a_s     = (float*)alloc((size_t)n * 4 * 4);
    float* a_d     = (float*)alloc((size_t)n * 4 * 4);
    float* bufA    = (float*)alloc((size_t)n * 64 * 4);
    float* bufB    = (float*)alloc((size_t)n * 64 * 4);
    float* bufC    = (float*)alloc((size_t)n * 64 * 4);
    int* p1 = (int*)bufC;  // packed sorted edges alias bufC (dead before C-P1 writes bufC)

    hipMemsetAsync(barrier, 0, 2 * 4, stream);

    megaA<<<GRID, 256, 0, stream>>>(x, srcp, dstp, W1, b1, hist_g, partial, bpre, excl,
                                    p1, csr, row_ptr, dinv, bufA, bufB, n, E, NBKT,
                                    barrier, barrier + 1);
    gemm2_gat<<<(n + 63) / 64, 256, 0, stream>>>(bufA, W2, b2, dinv, Wg, att_s, att_d,
                                                 a_s, a_d, bufB, n);
    megaC<<<GRID, 256, 0, stream>>>(row_ptr, csr, a_s, a_d, bg, W3, b3, dinv, Wg,
                                    att_s, att_d, Wl, bl, bufA, bufB, bufC, out, n,
                                    barrier, barrier + 1);
}

// Round 12
// 563.632 us; speedup vs baseline: 4.2008x; 4.2008x over previous
//
#include <hip/hip_runtime.h>
#include <math.h>

constexpr int KIN = 128;   // IN_F

// ---------------- graph build: MSD bucket sort (dst>>9), then per-bucket
// counting sort by dst&511. Produces csr, row_ptr, dinv with no global
// atomics and no scattered 4B stores. ----------------

// per-chunk histogram of dst>>9; hist_g layout [digit * NB + block]
__global__ void rx_hist(const int* __restrict__ dst, int* __restrict__ hist_g,
                        int E, int CH, int NB, int NBKT) {
    __shared__ int h[256];
    int b = blockIdx.x;
    for (int i = threadIdx.x; i < 256; i += blockDim.x) h[i] = 0;
    __syncthreads();
    int beg = b * CH, end = min(beg + CH, E);
    for (int e = beg + threadIdx.x; e < end; e += blockDim.x)
        atomicAdd(&h[dst[e] >> 9], 1);
    __syncthreads();
    for (int d = threadIdx.x; d < NBKT; d += blockDim.x)
        hist_g[d * NB + b] = h[d];
}

// generic 3-kernel exclusive scan over m ints
__global__ void gs_reduce(const int* __restrict__ a, int* __restrict__ bsum, int m) {
    __shared__ int s[256];
    int t = threadIdx.x;
    int i = blockIdx.x * 256 + t;
    s[t] = (i < m) ? a[i] : 0;
    __syncthreads();
    for (int off = 128; off > 0; off >>= 1) {
        if (t < off) s[t] += s[t + off];
        __syncthreads();
    }
    if (t == 0) bsum[blockIdx.x] = s[0];
}

__global__ void gs_blocksums(const int* __restrict__ bsum, int* __restrict__ bpre, int nb) {
    __shared__ int s[512];
    int t = threadIdx.x;
    int val = (t < nb) ? bsum[t] : 0;
    s[t] = val;
    __syncthreads();
    for (int off = 1; off < 512; off <<= 1) {
        int x = (t >= off) ? s[t - off] : 0;
        __syncthreads();
        s[t] += x;
        __syncthreads();
    }
    if (t < nb) bpre[t] = s[t] - val;  // exclusive
}

__global__ void gs_scatter(const int* __restrict__ a, const int* __restrict__ bpre,
                           int* __restrict__ out, int m) {
    __shared__ int s[256];
    int t = threadIdx.x;
    int i = blockIdx.x * 256 + t;
    int val = (i < m) ? a[i] : 0;
    s[t] = val;
    __syncthreads();
    for (int off = 1; off < 256; off <<= 1) {
        int x = (t >= off) ? s[t - off] : 0;
        __syncthreads();
        s[t] += x;
        __syncthreads();
    }
    if (i < m) out[i] = bpre[blockIdx.x] + s[t] - val;
}

// scatter edges into bucket order; per-(block,bucket) writes are sequential runs
__global__ void rx_scatter(const int* __restrict__ src, const int* __restrict__ dst,
                           const int* __restrict__ excl, int* __restrict__ s1,
                           int* __restrict__ d1, int E, int CH, int NB, int NBKT) {
    __shared__ int offs[256];
    int b = blockIdx.x;
    for (int d = threadIdx.x; d < NBKT; d += blockDim.x)
        offs[d] = excl[d * NB + b];
    __syncthreads();
    int beg = b * CH, end = min(beg + CH, E);
    for (int e = beg + threadIdx.x; e < end; e += blockDim.x) {
        int dd = dst[e];
        int pos = atomicAdd(&offs[dd >> 9], 1);
        s1[pos] = src[e];
        d1[pos] = dd;
    }
}

// one block per bucket: counting sort by dst&511 -> csr; also row_ptr + dinv
__global__ void __launch_bounds__(512)
bucket_sort(const int* __restrict__ s1, const int* __restrict__ d1,
            const int* __restrict__ excl, int* __restrict__ csr,
            int* __restrict__ row_ptr, float* __restrict__ dinv,
            int E, int NB, int NBKT, int n) {
    __shared__ int hist[512];
    __shared__ int scan[512];
    __shared__ int offs[512];
    int b = blockIdx.x, t = threadIdx.x;
    int base = excl[b * NB];
    int endb = (b + 1 < NBKT) ? excl[(b + 1) * NB] : E;
    hist[t] = 0;
    __syncthreads();
    for (int i = base + t; i < endb; i += 512)
        atomicAdd(&hist[d1[i] & 511], 1);
    __syncthreads();
    int v = hist[t];
    scan[t] = v;
    __syncthreads();
    for (int off = 1; off < 512; off <<= 1) {
        int x = (t >= off) ? scan[t - off] : 0;
        __syncthreads();
        scan[t] += x;
        __syncthreads();
    }
    int ex = scan[t] - v;  // exclusive prefix within bucket
    offs[t] = ex;
    int node = b * 512 + t;
    if (node < n) {
        row_ptr[node] = base + ex;
        dinv[node] = 1.0f / sqrtf((float)(v + 1));  // +1 self loop
    }
    if (b == NBKT - 1 && t == 0) row_ptr[n] = E;
    __syncthreads();
    for (int i = base + t; i < endb; i += 512) {
        int dd = d1[i];
        int pos = atomicAdd(&offs[dd & 511], 1);
        csr[base + pos] = s1[i];
    }
}

// ---------------- tiled register-blocked GEMM ----------------
template <int K, int F, int BM, int THREADS, bool SCALE, bool BRELU, bool ATT>
__global__ void __launch_bounds__(THREADS)
gemm_tile(const float* __restrict__ in, const float* __restrict__ W,
          const float* __restrict__ dinv, const float* __restrict__ bias,
          const float* __restrict__ att_src, const float* __restrict__ att_dst,
          float* __restrict__ a_s, float* __restrict__ a_d,
          float* __restrict__ out, int n) {
    constexpr int TM = 4, TN = 4;
    constexpr int TX = F / TN;
    constexpr int TY = BM / TM;
    static_assert(THREADS == TX * TY, "thread count mismatch");
    constexpr int K4 = K / 4;
    __shared__ float xs[K][BM];
    __shared__ float Ws[K * F];
    int t = threadIdx.x;
    int row0 = blockIdx.x * BM;

    for (int i = t; i < K * F / 4; i += THREADS)
        ((float4*)Ws)[i] = ((const float4*)W)[i];

    for (int i = t; i < BM * K4; i += THREADS) {
        int r = i % BM, k4 = i / BM;
        int row = row0 + r;
        float4 v = {0.f, 0.f, 0.f, 0.f};
        if (row < n) v = ((const float4*)(in + (size_t)row * K))[k4];
        xs[4 * k4 + 0][r] = v.x;
        xs[4 * k4 + 1][r] = v.y;
        xs[4 * k4 + 2][r] = v.z;
        xs[4 * k4 + 3][r] = v.w;
    }
    __syncthreads();

    int tx = t % TX, ty = t / TX;
    float acc[TM][TN] = {};
#pragma unroll 4
    for (int k = 0; k < K; ++k) {
        float4 xv = *(const float4*)&xs[k][ty * TM];
        float4 wv = *(const float4*)&Ws[k * F + tx * TN];
        float xr[4] = {xv.x, xv.y, xv.z, xv.w};
        float wr[4] = {wv.x, wv.y, wv.z, wv.w};
#pragma unroll
        for (int i = 0; i < TM; ++i)
#pragma unroll
            for (int j = 0; j < TN; ++j)
                acc[i][j] = fmaf(xr[i], wr[j], acc[i][j]);
    }

#pragma unroll
    for (int i = 0; i < TM; ++i) {
        int row = row0 + ty * TM + i;
        if (row >= n) continue;
        float s = SCALE ? dinv[row] : 1.0f;
        float4 o;
        if (BRELU) {
            o.x = fmaxf(fmaf(acc[i][0], s, bias[4 * tx + 0]), 0.f);
            o.y = fmaxf(fmaf(acc[i][1], s, bias[4 * tx + 1]), 0.f);
            o.z = fmaxf(fmaf(acc[i][2], s, bias[4 * tx + 2]), 0.f);
            o.w = fmaxf(fmaf(acc[i][3], s, bias[4 * tx + 3]), 0.f);
        } else {
            o.x = acc[i][0] * s; o.y = acc[i][1] * s;
            o.z = acc[i][2] * s; o.w = acc[i][3] * s;
        }
        ((float4*)(out + (size_t)row * F))[tx] = o;
    }
    if (ATT) {
        int hd = tx >> 2;
        float as0 = att_src[4 * tx + 0], as1 = att_src[4 * tx + 1];
        float as2 = att_src[4 * tx + 2], as3 = att_src[4 * tx + 3];
        float ad0 = att_dst[4 * tx + 0], ad1 = att_dst[4 * tx + 1];
        float ad2 = att_dst[4 * tx + 2], ad3 = att_dst[4 * tx + 3];
#pragma unroll
        for (int i = 0; i < TM; ++i) {
            float ps = acc[i][0] * as0 + acc[i][1] * as1 + acc[i][2] * as2 + acc[i][3] * as3;
            float pd = acc[i][0] * ad0 + acc[i][1] * ad1 + acc[i][2] * ad2 + acc[i][3] * ad3;
            ps += __shfl_xor(ps, 1); pd += __shfl_xor(pd, 1);
            ps += __shfl_xor(ps, 2); pd += __shfl_xor(pd, 2);
            int row = row0 + ty * TM + i;
            if ((tx & 3) == 0 && row < n) {
                a_s[row * 4 + hd] = ps;
                a_d[row * 4 + hd] = pd;
            }
        }
    }
}

// ---------------- fused layer2-GEMM + GAT1-GEMM ----------------
__global__ void __launch_bounds__(256)
gemm2_gat(const float* __restrict__ T, const float* __restrict__ W2,
          const float* __restrict__ b2, const float* __restrict__ dinv,
          const float* __restrict__ Wg, const float* __restrict__ att_src,
          const float* __restrict__ att_dst, float* __restrict__ a_s,
          float* __restrict__ a_d, float* __restrict__ A1, int n) {
    __shared__ float xs[32][64];
    __shared__ float W2s[32 * 64];
    __shared__ float Wgs[64 * 64];
    __shared__ float hs[64][68];
    int t = threadIdx.x;
    int row0 = blockIdx.x * 64;

    for (int i = t; i < 32 * 64 / 4; i += 256) ((float4*)W2s)[i] = ((const float4*)W2)[i];
    for (int i = t; i < 64 * 64 / 4; i += 256) ((float4*)Wgs)[i] = ((const float4*)Wg)[i];
    for (int i = t; i < 64 * 8; i += 256) {
        int r = i % 64, k4 = i / 64;
        int row = row0 + r;
        float4 v = {0.f, 0.f, 0.f, 0.f};
        if (row < n) v = ((const float4*)(T + (size_t)row * 32))[k4];
        xs[4 * k4 + 0][r] = v.x;
        xs[4 * k4 + 1][r] = v.y;
        xs[4 * k4 + 2][r] = v.z;
        xs[4 * k4 + 3][r] = v.w;
    }
    __syncthreads();

    int tx = t % 16, ty = t / 16;
    {
        float acc[4][4] = {};
#pragma unroll 4
        for (int k = 0; k < 32; ++k) {
            float4 xv = *(const float4*)&xs[k][ty * 4];
            float4 wv = *(const float4*)&W2s[k * 64 + tx * 4];
            float xr[4] = {xv.x, xv.y, xv.z, xv.w};
            float wr[4] = {wv.x, wv.y, wv.z, wv.w};
#pragma unroll
            for (int i = 0; i < 4; ++i)
#pragma unroll
                for (int j = 0; j < 4; ++j)
                    acc[i][j] = fmaf(xr[i], wr[j], acc[i][j]);
        }
#pragma unroll
        for (int i = 0; i < 4; ++i) {
            int row = row0 + ty * 4 + i;
            float s = (row < n) ? dinv[row] : 0.f;
#pragma unroll
            for (int j = 0; j < 4; ++j)
                hs[4 * tx + j][ty * 4 + i] = fmaxf(fmaf(acc[i][j], s, b2[4 * tx + j]), 0.f);
        }
    }
    __syncthreads();

    float acc[4][4] = {};
#pragma unroll 4
    for (int k = 0; k < 64; ++k) {
        float4 xv = *(const float4*)&hs[k][ty * 4];
        float4 wv = *(const float4*)&Wgs[k * 64 + tx * 4];
        float xr[4] = {xv.x, xv.y, xv.z, xv.w};
        float wr[4] = {wv.x, wv.y, wv.z, wv.w};
#pragma unroll
        for (int i = 0; i < 4; ++i)
#pragma unroll
            for (int j = 0; j < 4; ++j)
                acc[i][j] = fmaf(xr[i], wr[j], acc[i][j]);
    }
#pragma unroll
    for (int i = 0; i < 4; ++i) {
        int row = row0 + ty * 4 + i;
        if (row >= n) continue;
        float4 o = {acc[i][0], acc[i][1], acc[i][2], acc[i][3]};
        ((float4*)(A1 + (size_t)row * 64))[tx] = o;
    }
    {
        int hd = tx >> 2;
        float as0 = att_src[4 * tx + 0], as1 = att_src[4 * tx + 1];
        float as2 = att_src[4 * tx + 2], as3 = att_src[4 * tx + 3];
        float ad0 = att_dst[4 * tx + 0], ad1 = att_dst[4 * tx + 1];
        float ad2 = att_dst[4 * tx + 2], ad3 = att_dst[4 * tx + 3];
#pragma unroll
        for (int i = 0; i < 4; ++i) {
            float ps = acc[i][0] * as0 + acc[i][1] * as1 + acc[i][2] * as2 + acc[i][3] * as3;
            float pd = acc[i][0] * ad0 + acc[i][1] * ad1 + acc[i][2] * ad2 + acc[i][3] * ad3;
            ps += __shfl_xor(ps, 1); pd += __shfl_xor(pd, 1);
            ps += __shfl_xor(ps, 2); pd += __shfl_xor(pd, 2);
            int row = row0 + ty * 4 + i;
            if ((tx & 3) == 0 && row < n) {
                a_s[row * 4 + hd] = ps;
                a_d[row * 4 + hd] = pd;
            }
        }
    }
}

// ---------------- aggregation kernels (depth-1 pipeline) ----------------
// MODE 0: out = relu(dinv*acc + b) (+res)   MODE 1: out = dinv*relu(dinv*acc + b)
// MODE 2: out = acc (raw sum)
template <int F, int MODE, bool RES>
__global__ void gcn_agg_w(const float* __restrict__ Hs, const int* __restrict__ row_ptr,
                          const int* __restrict__ csr, const float* __restrict__ dinv,
                          const float* __restrict__ bias, const float* __restrict__ res,
                          float* __restrict__ out, int n) {
    constexpr int CG = F / 4;
    constexpr int SLOTS = 64 / CG;
    int idx = blockIdx.x * blockDim.x + threadIdx.x;
    int v = idx >> 6;
    int lane = idx & 63;
    if (v >= n) return;
    int cg = lane % CG;
    int slot = lane / CG;
    const float4* H4 = (const float4*)Hs;

    float4 acc = {0.f, 0.f, 0.f, 0.f};
    if (slot == 0) acc = H4[(size_t)v * CG + cg];  // self loop

    int beg = row_ptr[v], end = row_ptr[v + 1];
    int iters = (end - beg + SLOTS - 1) / SLOTS;
    int e = beg + slot;
    bool val = e < end;
    int u = val ? csr[e] : v;
    float4 h = H4[(size_t)u * CG + cg];
    for (int i = 0; i < iters; ++i) {
        int en = e + SLOTS;
        bool valn = en < end;
        int un = valn ? csr[en] : v;
        float4 hn = H4[(size_t)un * CG + cg];
        float m = val ? 1.f : 0.f;
        acc.x = fmaf(m, h.x, acc.x);
        acc.y = fmaf(m, h.y, acc.y);
        acc.z = fmaf(m, h.z, acc.z);
        acc.w = fmaf(m, h.w, acc.w);
        e = en; val = valn; h = hn;
    }
    for (int off = CG; off < 64; off <<= 1) {
        acc.x += __shfl_xor(acc.x, off);
        acc.y += __shfl_xor(acc.y, off);
        acc.z += __shfl_xor(acc.z, off);
        acc.w += __shfl_xor(acc.w, off);
    }
    if (slot == 0) {
        float4 o;
        if (MODE == 2) {
            o = acc;
        } else {
            float dv = dinv[v];
            o.x = fmaxf(fmaf(dv, acc.x, bias[4 * cg + 0]), 0.f);
            o.y = fmaxf(fmaf(dv, acc.y, bias[4 * cg + 1]), 0.f);
            o.z = fmaxf(fmaf(dv, acc.z, bias[4 * cg + 2]), 0.f);
            o.w = fmaxf(fmaf(dv, acc.w, bias[4 * cg + 3]), 0.f);
            if (MODE == 1) { o.x *= dv; o.y *= dv; o.z *= dv; o.w *= dv; }
            if (RES) {
                const float4 r = ((const float4*)res)[(size_t)v * CG + cg];
                o.x += r.x; o.y += r.y; o.z += r.z; o.w += r.w;
            }
        }
        ((float4*)out)[(size_t)v * CG + cg] = o;
    }
}

template <bool FINAL>
__global__ void gat_agg_w(const float* __restrict__ H, const int* __restrict__ row_ptr,
                          const int* __restrict__ csr, const float* __restrict__ a_s,
                          const float* __restrict__ a_d, const float* __restrict__ bias,
                          const float* __restrict__ Wl, const float* __restrict__ bl,
                          float* __restrict__ out, int n) {
    int idx = blockIdx.x * blockDim.x + threadIdx.x;
    int v = idx >> 6;
    int lane = idx & 63;
    if (v >= n) return;
    int cg = lane & 15;
    int slot = lane >> 4;
    int hd = cg >> 2;
    const float4* H4 = (const float4*)H;

    float adv = a_d[v * 4 + hd];
    float l = 0.f;
    float4 acc = {0.f, 0.f, 0.f, 0.f};
    if (slot == 0) {  // self edge
        float e0 = a_s[v * 4 + hd] + adv;
        e0 = (e0 >= 0.f) ? e0 : 0.2f * e0;
        float p = __expf(e0);
        l = p;
        float4 h = H4[(size_t)v * 16 + cg];
        acc.x = p * h.x; acc.y = p * h.y; acc.z = p * h.z; acc.w = p * h.w;
    }
    int beg = row_ptr[v], end = row_ptr[v + 1];
    int iters = (end - beg + 3) >> 2;
    int e = beg + slot;
    bool val = e < end;
    int u = val ? csr[e] : v;
    float4 h = H4[(size_t)u * 16 + cg];
    float as = a_s[u * 4 + hd];
    for (int i = 0; i < iters; ++i) {
        int en = e + 4;
        bool valn = en < end;
        int un = valn ? csr[en] : v;
        float4 hn = H4[(size_t)un * 16 + cg];
        float asn = a_s[un * 4 + hd];
        float ev = as + adv;
        ev = (ev >= 0.f) ? ev : 0.2f * ev;
        float p = val ? __expf(ev) : 0.f;
        l += p;
        acc.x = fmaf(p, h.x, acc.x);
        acc.y = fmaf(p, h.y, acc.y);
        acc.z = fmaf(p, h.z, acc.z);
        acc.w = fmaf(p, h.w, acc.w);
        e = en; val = valn; h = hn; as = asn;
    }
    for (int off = 16; off < 64; off <<= 1) {
        l += __shfl_xor(l, off);
        acc.x += __shfl_xor(acc.x, off);
        acc.y += __shfl_xor(acc.y, off);
        acc.z += __shfl_xor(acc.z, off);
        acc.w += __shfl_xor(acc.w, off);
    }
    float rl = 1.0f / (l + 1e-16f);
    if (!FINAL) {
        if (slot == 0) {
            float4 o;
            o.x = fmaxf(fmaf(acc.x, rl, bias[4 * cg + 0]), 0.f);
            o.y = fmaxf(fmaf(acc.y, rl, bias[4 * cg + 1]), 0.f);
            o.z = fmaxf(fmaf(acc.z, rl, bias[4 * cg + 2]), 0.f);
            o.w = fmaxf(fmaf(acc.w, rl, bias[4 * cg + 3]), 0.f);
            ((float4*)out)[(size_t)v * 16 + cg] = o;
        }
    } else {
        float p = fmaxf(fmaf(acc.x, rl, bias[4 * cg + 0]), 0.f) * Wl[4 * cg + 0]
                + fmaxf(fmaf(acc.y, rl, bias[4 * cg + 1]), 0.f) * Wl[4 * cg + 1]
                + fmaxf(fmaf(acc.z, rl, bias[4 * cg + 2]), 0.f) * Wl[4 * cg + 2]
                + fmaxf(fmaf(acc.w, rl, bias[4 * cg + 3]), 0.f) * Wl[4 * cg + 3];
        p += __shfl_xor(p, 1);
        p += __shfl_xor(p, 2);
        p += __shfl_xor(p, 4);
        p += __shfl_xor(p, 8);
        if (lane == 0) out[v] = fmaxf(p + bl[0], 0.f);
    }
}

// ---------------- launch ----------------

extern "C" void kernel_launch(void* const* d_in, const int* in_sizes, int n_in,
                              void* d_out, int out_size, void* d_ws, size_t ws_size,
                              hipStream_t stream) {
    const float* x     = (const float*)d_in[0];
    const int*   ei    = (const int*)d_in[1];
    const float* W1    = (const float*)d_in[2];
    const float* b1    = (const float*)d_in[3];
    const float* W2    = (const float*)d_in[4];
    const float* b2    = (const float*)d_in[5];
    const float* W3    = (const float*)d_in[6];
    const float* b3    = (const float*)d_in[7];
    const float* Wg    = (const float*)d_in[8];
    const float* att_s = (const float*)d_in[9];
    const float* att_d = (const float*)d_in[10];
    const float* bg    = (const float*)d_in[11];
    const float* Wl    = (const float*)d_in[12];
    const float* bl    = (const float*)d_in[13];
    float* out = (float*)d_out;

    int n = in_sizes[0] / KIN;  // 100000
    int E = in_sizes[1] / 2;    // 1600000
    const int* srcp = ei;
    const int* dstp = ei + E;

    // radix parameters
    int NB = 128;                      // chunks
    int CH = (E + NB - 1) / NB;        // edges per chunk
    int NBKT = (n + 511) >> 9;         // dst buckets of 512 nodes
    int M = NBKT * NB;                 // hist entries

    char* w = (char*)d_ws;
    auto alloc = [&](size_t bytes) -> void* {
        void* p = (void*)w;
        w += (bytes + 255) & ~(size_t)255;
        return p;
    };
    int*   row_ptr = (int*)alloc((size_t)(n + 1) * 4);
    int*   csr     = (int*)alloc((size_t)E * 4);
    int*   hist_g  = (int*)alloc((size_t)M * 4);
    int*   excl    = (int*)alloc((size_t)M * 4);
    int*   bsum    = (int*)alloc(512 * 4);
    int*   bpre    = (int*)alloc(512 * 4);
    float* dinv    = (float*)alloc((size_t)n * 4);
    float* a_s     = (float*)alloc((size_t)n * 4 * 4);
    float* a_d     = (float*)alloc((size_t)n * 4 * 4);
    float* bufA    = (float*)alloc((size_t)n * 64 * 4);
    float* bufB    = (float*)alloc((size_t)n * 64 * 4);
    float* bufC    = (float*)alloc((size_t)n * 64 * 4);
    // bucket-sorted edge arrays alias bufB (dead before first dense write of bufB)
    int* s1 = (int*)bufB;
    int* d1 = ((int*)bufB) + E;

    int msb = (M + 255) / 256;
    rx_hist<<<NB, 256, 0, stream>>>(dstp, hist_g, E, CH, NB, NBKT);
    gs_reduce<<<msb, 256, 0, stream>>>(hist_g, bsum, M);
    gs_blocksums<<<1, 512, 0, stream>>>(bsum, bpre, msb);
    gs_scatter<<<msb, 256, 0, stream>>>(hist_g, bpre, excl, M);
    rx_scatter<<<NB, 256, 0, stream>>>(srcp, dstp, excl, s1, d1, E, CH, NB, NBKT);
    bucket_sort<<<NBKT, 512, 0, stream>>>(s1, d1, excl, csr, row_ptr, dinv, E, NB, NBKT, n);

    int agg_blocks = (n * 64 + 255) / 256;
    int gemm_blocks = (n + 63) / 64;

    // Layer 1: GCN 128->32. H1s = dinv⊙(X@W1); agg emits G = dinv*relu(dinv*agg+b1)
    gemm_tile<128, 32, 64, 128, true, false, false><<<gemm_blocks, 128, 0, stream>>>(
        x, W1, dinv, nullptr, nullptr, nullptr, nullptr, nullptr, bufA, n);
    gcn_agg_w<32, 1, false><<<agg_blocks, 256, 0, stream>>>(bufA, row_ptr, csr, dinv, b1, nullptr, bufB, n);
    // Layer 2 agg in 32-dim (raw sum T)
    gcn_agg_w<32, 2, false><<<agg_blocks, 256, 0, stream>>>(bufB, row_ptr, csr, nullptr, nullptr, nullptr, bufA, n);
    // Fused: h2 = relu(dinv*T@W2+b2) (LDS only); A1 = h2@Wg; attention dots
    gemm2_gat<<<gemm_blocks, 256, 0, stream>>>(bufA, W2, b2, dinv, Wg, att_s, att_d, a_s, a_d, bufB, n);
    gat_agg_w<false><<<agg_blocks, 256, 0, stream>>>(bufB, row_ptr, csr, a_s, a_d, bg, nullptr, nullptr, bufC, n);
    // GCN 3 + residual
    gemm_tile<64, 64, 64, 256, true, false, false><<<gemm_blocks, 256, 0, stream>>>(
        bufC, W3, dinv, nullptr, nullptr, nullptr, nullptr, nullptr, bufA, n);
    gcn_agg_w<64, 0, true><<<agg_blocks, 256, 0, stream>>>(bufA, row_ptr, csr, dinv, b3, bufC, bufB, n);
    // GAT 2 (gemm + fused attention dots) + fused final linear
    gemm_tile<64, 64, 64, 256, false, false, true><<<gemm_blocks, 256, 0, stream>>>(
        bufB, Wg, nullptr, nullptr, att_s, att_d, a_s, a_d, bufA, n);
    gat_agg_w<true><<<agg_blocks, 256, 0, stream>>>(bufA, row_ptr, csr, a_s, a_d, bg, Wl, bl, out, n);
}